// Round 8
// baseline (287.151 us; speedup 1.0000x reference)
//
#include <hip/hip_runtime.h>
#include <hip/hip_bf16.h>

// Problem constants
#define BATCH 256
#define DIM   2048
#define NMEM  16384   // C_CAM * P
#define PCLS  2048
#define CCAM  8
#define KSEL  50
#define T_INV 14.285714285714285714f   // 1 / 0.07
#define NBIN  4096

typedef __bf16 bf16x8 __attribute__((ext_vector_type(8)));
typedef float  f32x4  __attribute__((ext_vector_type(4)));

#define AS_GLOBAL __attribute__((address_space(1)))
#define AS_LDS    __attribute__((address_space(3)))

// s_waitcnt immediates (gfx9 encoding): vmcnt[3:0]|[15:14], expcnt[6:4]=7,
// lgkmcnt[11:8]=15 (i.e., only constrain vmcnt)
#define WAITCNT_VM3 0xF73
#define WAITCNT_VM0 0xF70

static __device__ __forceinline__ unsigned int f2bf(float f) {
  unsigned int u = __float_as_uint(f);
  return (u + 0x7FFFu + ((u >> 16) & 1u)) >> 16;   // RNE truncate to bf16
}
static __device__ __forceinline__ unsigned int pk2(float lo, float hi) {
  return f2bf(lo) | (f2bf(hi) << 16);
}
// logits are cosine sims in [-1,1]; map to bin 0..4095 (masked -1e30 -> bin 0)
static __device__ __forceinline__ int binof(float v) {
  float bf = fmaf(v, 1950.4762f, 2048.0f);     // 4096 / 2.1 scale
  bf = fminf(fmaxf(bf, 0.0f), 4095.0f);
  return (int)bf;
}

// ---------------------------------------------------------------------------
// Kernel 1: row-normalize inputs, cast to bf16.  grid=256 blocks x 256 thr
// ---------------------------------------------------------------------------
__global__ __launch_bounds__(256) void norm_cast_kernel(
    const float* __restrict__ in, unsigned short* __restrict__ xb) {
  __shared__ float red[256];
  const int b = blockIdx.x, t = threadIdx.x;
  const float4* row = (const float4*)(in + (size_t)b * DIM);
  float4 a0 = row[t];
  float4 a1 = row[t + 256];
  float ss = a0.x*a0.x + a0.y*a0.y + a0.z*a0.z + a0.w*a0.w
           + a1.x*a1.x + a1.y*a1.y + a1.z*a1.z + a1.w*a1.w;
  red[t] = ss; __syncthreads();
  for (int s = 128; s > 0; s >>= 1) { if (t < s) red[t] += red[t + s]; __syncthreads(); }
  const float rn = rsqrtf(red[0]);
  ushort4 o0, o1;
  o0.x = (unsigned short)f2bf(a0.x*rn); o0.y = (unsigned short)f2bf(a0.y*rn);
  o0.z = (unsigned short)f2bf(a0.z*rn); o0.w = (unsigned short)f2bf(a0.w*rn);
  o1.x = (unsigned short)f2bf(a1.x*rn); o1.y = (unsigned short)f2bf(a1.y*rn);
  o1.z = (unsigned short)f2bf(a1.z*rn); o1.w = (unsigned short)f2bf(a1.w*rn);
  *(ushort4*)&xb[(size_t)b * DIM + t * 4]         = o0;
  *(ushort4*)&xb[(size_t)b * DIM + (t + 256) * 4] = o1;
}

// ---------------------------------------------------------------------------
// Kernel 2: logits += x(bf16) @ tempV^T over a K-half.
// BM=256 (full batch: V read from HBM exactly once), BN=64, BK=32.
// 512 thr = 8 waves (4M x 2N), wave tile 64x32 (4x2 frags, 8 MFMA/tile).
// TRIPLE-buffered LDS (3 x 24 KB) + glds(width16) + RAW s_barrier with
// manual s_waitcnt vmcnt(3): loads for tile k+1 stay in flight across the
// barrier (never drain to 0) -> continuous HBM request flow (the AITER
// pattern, m139 precedent). Writer is 2 tiles ahead of slowest reader ->
// no overwrite race with a single barrier per tile.
// grid = dim3(1, 256 Ntiles, 2 Ksplit) = 512 blocks -> 2 blocks/CU (144 KB).
// C accumulated with fp32 atomic add (2 commutative addends/elem ->
// deterministic); logits pre-zeroed via hipMemsetAsync.
// LDS unpadded (glds requirement); conflicts broken by 16B-chunk XOR swizzle
// on the global-address side (same family as R6/R7, measured 0 conflicts):
//   A (bf16, 64 B/row, 4 chunks):  phys p = c ^ (row & 3)
//   B (fp32, 128 B/row, 8 chunks): phys p = c ^ (row & 7)
// ---------------------------------------------------------------------------
#define BM 256
#define BN 64
#define BK 32
#define KHALF (DIM / 2)      // 1024
#define NT    (KHALF / BK)   // 32 tiles per block

__global__ __launch_bounds__(512, 4) void gemm_kernel(
    const unsigned short* __restrict__ X,   // [256][2048] bf16
    const float* __restrict__ V,            // [16384][2048] fp32
    float* __restrict__ C) {                // [256][16384] fp32 (pre-zeroed)
  __shared__ __align__(16) unsigned short As[3][BM * BK];  // 3 x 16 KB
  __shared__ __align__(16) float          Bs[3][BN * BK];  // 3 x 8 KB
  const int t  = threadIdx.x;
  const int n0 = blockIdx.y * BN;
  const int kb = blockIdx.z * KHALF;
  const int lane = t & 63;
  const int w    = t >> 6;          // 0..7
  const int wm   = (w >> 1) * 64;   // 0,64,128,192
  const int wn   = (w & 1) * 32;    // 0,32
  const int fr   = lane & 15;
  const int fko  = lane >> 4;       // 0..3

  f32x4 acc[4][2];
#pragma unroll
  for (int i = 0; i < 4; i++)
#pragma unroll
    for (int j = 0; j < 2; j++) acc[i][j] = (f32x4){0.f, 0.f, 0.f, 0.f};

  // glds per-lane global source addresses (swizzled):
  // A: wave w instr q covers rows w*32+q*16 .. +16 (16 rows x 64 B = 1024 B)
  //    lane l -> row +l/4, phys chunk l%4, logical chunk (l%4)^((l/4)&3)
  const unsigned short* Xp =
      X + (size_t)(w * 32 + (lane >> 2)) * DIM + kb
        + (((lane & 3) ^ ((lane >> 2) & 3)) * 8);
  // B: wave w covers rows w*8 .. +8 (8 rows x 128 B = 1024 B)
  //    lane l -> row +l/8, phys chunk l%8, logical chunk (l%8)^((l/8)&7)
  const float* Vp =
      V + (size_t)(n0 + w * 8 + (lane >> 3)) * DIM + kb
        + (((lane & 7) ^ ((lane >> 3) & 7)) * 4);

  auto glds_tile = [&](int buf, int k0) {   // 3 glds per wave
#pragma unroll
    for (int q = 0; q < 2; q++) {
      __builtin_amdgcn_global_load_lds(
          (const AS_GLOBAL unsigned int*)(Xp + (size_t)q * 16 * DIM + k0),
          (AS_LDS unsigned int*)&As[buf][(w * 32 + q * 16) * BK],
          16, 0, 0);
    }
    __builtin_amdgcn_global_load_lds(
        (const AS_GLOBAL unsigned int*)(Vp + k0),
        (AS_LDS unsigned int*)&Bs[buf][(w * 8) * BK],
        16, 0, 0);
  };

  auto compute = [&](int buf) {
    bf16x8 aF[4], bF[2];
    const int pa = fko ^ (fr & 3);           // A phys chunk
#pragma unroll
    for (int i = 0; i < 4; i++) {
      const int R = wm + i * 16 + fr;
      aF[i] = *(const bf16x8*)&As[buf][R * BK + pa * 8];
    }
    const int p0 = (2 * fko) ^ (fr & 7);     // B phys chunk pair
#pragma unroll
    for (int j = 0; j < 2; j++) {
      const int RN = wn + j * 16 + fr;
      const float4* Brow = (const float4*)&Bs[buf][RN * BK];
      const float4 lo = Brow[p0];
      const float4 hi = Brow[p0 ^ 1];
      uint4 pk;
      pk.x = pk2(lo.x, lo.y); pk.y = pk2(lo.z, lo.w);
      pk.z = pk2(hi.x, hi.y); pk.w = pk2(hi.z, hi.w);
      bF[j] = *(bf16x8*)&pk;
    }
#pragma unroll
    for (int i = 0; i < 4; i++)
#pragma unroll
      for (int j = 0; j < 2; j++)
        acc[i][j] = __builtin_amdgcn_mfma_f32_16x16x32_bf16(aF[i], bF[j], acc[i][j], 0, 0, 0);
  };

  // prologue: tile 0 in flight
  glds_tile(0, 0);

  int cur = 0;
  for (int kt = 0; kt < NT; kt++) {
    if (kt + 1 < NT) {
      int nxt = cur + 1; if (nxt == 3) nxt = 0;
      glds_tile(nxt, (kt + 1) * BK);            // keep 3 loads in flight
      __builtin_amdgcn_s_waitcnt(WAITCNT_VM3);  // tile kt landed; kt+1 flying
    } else {
      __builtin_amdgcn_s_waitcnt(WAITCNT_VM0);
    }
    __builtin_amdgcn_s_barrier();               // raw: no vmcnt(0) drain
    __builtin_amdgcn_sched_barrier(0);          // pin: no ds_read hoists above
    compute(cur);
    cur = cur + 1; if (cur == 3) cur = 0;
  }

  // epilogue: C/D layout col=lane&15, row=(lane>>4)*4+reg  [m89/m91 verified]
  // fp32 atomic add: 2 addends per element (K-split), commutative -> determ.
  const int cr = (lane >> 4) * 4;
  const int cc = lane & 15;
#pragma unroll
  for (int i = 0; i < 4; i++)
#pragma unroll
    for (int j = 0; j < 2; j++)
#pragma unroll
      for (int r = 0; r < 4; r++)
        unsafeAtomicAdd(
            &C[(size_t)(wm + i * 16 + cr + r) * NMEM + (n0 + wn + j * 16 + cc)],
            acc[i][j][r]);
}

// ---------------------------------------------------------------------------
// Kernel 3: per-row losses. One block (256 thr) per sample.
//  - intra CE over own camera bank (no max-sub: exp(v*14.3) <= 1.6e6, fp32 ok)
//  - mask 8 positives
//  - EXACT top-50 via 4096-bin LDS histogram + suffix scan; bins above the
//    boundary bin sum directly, boundary bin resolved exactly (few elems)
//  - inter logsumexp over {8 ori, 50 sel}
// ---------------------------------------------------------------------------
__global__ __launch_bounds__(256) void row_loss_kernel(
    const float* __restrict__ logits,
    const int* __restrict__ labels, const int* __restrict__ cams,
    float* __restrict__ ce_out, float* __restrict__ lossk_out) {
  __shared__ float vals[NMEM];      // 64 KB
  __shared__ int   hist[NBIN];      // 16 KB
  __shared__ float red[256];
  __shared__ int   pint[256];
  __shared__ float bl[512];         // boundary-bin value list
  __shared__ int   bcount;
  __shared__ int   bstar_s, cabove_s;

  const int b = blockIdx.x, t = threadIdx.x;
  const float4* src = (const float4*)(logits + (size_t)b * NMEM);
#pragma unroll
  for (int i = 0; i < 16; i++) ((float4*)vals)[t + 256 * i] = src[t + 256 * i];
#pragma unroll
  for (int i = 0; i < NBIN / 256; i++) hist[t + 256 * i] = 0;
  if (t == 0) bcount = 0;
  const int cam = cams[b], label = labels[b];
  __syncthreads();

  // ---- intra CE over [cam*PCLS, +PCLS) ----
  const int s0 = cam * PCLS;
  float S = 0.f;
#pragma unroll
  for (int i = 0; i < 8; i++) S += __expf(vals[s0 + t + 256 * i] * T_INV);
  red[t] = S; __syncthreads();
  for (int s = 128; s > 0; s >>= 1) { if (t < s) red[t] += red[t + s]; __syncthreads(); }
  float ov[CCAM]; float sumo = 0.f;
  if (t == 0) {
    ce_out[b] = logf(red[0]) - vals[s0 + label] * T_INV;
#pragma unroll
    for (int c = 0; c < CCAM; c++) { ov[c] = vals[c * PCLS + label]; sumo += ov[c]; }
  }
  __syncthreads();                 // t0's ov reads done before masking
  if (t < CCAM) vals[t * PCLS + label] = -1e30f;
  __syncthreads();

  // ---- histogram ----
#pragma unroll
  for (int i = 0; i < 64; i++) {
    int bin = binof(vals[t + 256 * i]);
    atomicAdd(&hist[bin], 1);
  }
  __syncthreads();

  // ---- suffix scan: find boundary bin b* with S(b*) >= K > S(b*+1) ----
  int ps = 0;
#pragma unroll
  for (int i = 0; i < 16; i++) ps += hist[t * 16 + i];
  pint[t] = ps; __syncthreads();
  if (t == 0) {
    int cum = 0, bstar = 0, cab = 0;
    for (int tc = 255; tc >= 0; tc--) {
      if (cum + pint[tc] >= KSEL) {
        for (int bi = tc * 16 + 15; bi >= tc * 16; bi--) {
          int h = hist[bi];
          if (cum + h >= KSEL) { bstar = bi; cab = cum; break; }
          cum += h;
        }
        break;
      }
      cum += pint[tc];
    }
    bstar_s = bstar; cabove_s = cab;
  }
  __syncthreads();
  const int bstar = bstar_s;

  // ---- selection pass: sum exp over bins > b*, collect boundary bin ----
  float S2 = 0.f;
#pragma unroll
  for (int i = 0; i < 64; i++) {
    float v = vals[t + 256 * i];
    int bin = binof(v);
    if (bin > bstar) S2 += __expf(v * T_INV);
    else if (bin == bstar) {
      int p = atomicAdd(&bcount, 1);
      if (p < 512) bl[p] = v;
    }
  }
  red[t] = S2; __syncthreads();
  for (int s = 128; s > 0; s >>= 1) { if (t < s) red[t] += red[t + s]; __syncthreads(); }

  if (t == 0) {
    float S2tot = red[0];
    int need = KSEL - cabove_s;
    int bc = min(bcount, 512);
    for (int r = 0; r < need; r++) {         // exact top-(need) of boundary bin
      float mx = -1e30f; int mi = 0;
      for (int i = 0; i < bc; i++) if (bl[i] > mx) { mx = bl[i]; mi = i; }
      S2tot += __expf(mx * T_INV);
      bl[mi] = -1e30f;
    }
#pragma unroll
    for (int c = 0; c < CCAM; c++) S2tot += __expf(ov[c] * T_INV);
    lossk_out[b] = logf(S2tot) - (sumo * T_INV) * (1.0f / CCAM);
  }
}

// ---------------------------------------------------------------------------
// Kernel 4: deterministic per-camera segment means -> 2 scalars.
// ---------------------------------------------------------------------------
__global__ __launch_bounds__(256) void finalize_kernel(
    const float* __restrict__ ce, const float* __restrict__ lossk,
    const int* __restrict__ cams, float* __restrict__ out) {
  __shared__ float ce_s[BATCH], lk_s[BATCH];
  __shared__ int   cam_s[BATCH];
  __shared__ float si[CCAM], sk[CCAM], cnt[CCAM];
  const int t = threadIdx.x;
  ce_s[t]  = ce[t];
  lk_s[t]  = lossk[t];
  cam_s[t] = cams[t];
  __syncthreads();
  if (t < CCAM) {
    float a = 0.f, b = 0.f; int n = 0;
    for (int i = 0; i < BATCH; i++) {
      if (cam_s[i] == t) { a += ce_s[i]; b += lk_s[i]; n++; }
    }
    si[t] = a; sk[t] = b; cnt[t] = (float)n;
  }
  __syncthreads();
  if (t == 0) {
    float li = 0.f, lk = 0.f;
    for (int c = 0; c < CCAM; c++) {
      if (cnt[c] > 0.f) { li += si[c] / cnt[c]; lk += sk[c] / cnt[c]; }
    }
    out[0] = li;
    out[1] = 0.5f * lk;
  }
}

// ---------------------------------------------------------------------------
extern "C" void kernel_launch(void* const* d_in, const int* in_sizes, int n_in,
                              void* d_out, int out_size, void* d_ws, size_t ws_size,
                              hipStream_t stream) {
  const float* inputs = (const float*)d_in[0];   // [256][2048]
  const int*   labels = (const int*)d_in[1];     // [256]
  const int*   cams   = (const int*)d_in[2];     // [256]
  const float* tempV  = (const float*)d_in[3];   // [16384][2048]
  float* out = (float*)d_out;

  char* ws = (char*)d_ws;
  unsigned short* xb  = (unsigned short*)ws;                       // 1 MB
  float* logits       = (float*)(ws + (1u << 20));                 // 16 MB
  float* ce           = (float*)(ws + (1u << 20) + (16u << 20));   // 1 KB
  float* lossk        = (float*)(ws + (1u << 20) + (16u << 20) + 1024);

  norm_cast_kernel<<<BATCH, 256, 0, stream>>>(inputs, xb);
  hipMemsetAsync(logits, 0, (size_t)BATCH * NMEM * sizeof(float), stream);
  gemm_kernel<<<dim3(1, NMEM / BN, 2), 512, 0, stream>>>(xb, tempV, logits);
  row_loss_kernel<<<BATCH, 256, 0, stream>>>(logits, labels, cams, ce, lossk);
  finalize_kernel<<<1, 256, 0, stream>>>(ce, lossk, cams, out);
}